// Round 22
// baseline (144.659 us; speedup 1.0000x reference)
//
#include <hip/hip_runtime.h>
#include <stdint.h>
#include <stddef.h>

typedef __attribute__((ext_vector_type(8)))  short bf16x8;
typedef __attribute__((ext_vector_type(2)))  float f32x2;
typedef __attribute__((ext_vector_type(4)))  float f32x4;
typedef __attribute__((ext_vector_type(16))) float f32x16;
typedef __attribute__((ext_vector_type(4)))  float float4v;
typedef __attribute__((ext_vector_type(4)))  int   int4v;

#define DEV static __device__ __forceinline__

static constexpr int EMBED  = 1024;
static constexpr int HEADS  = 16;
static constexpr int SEQ    = 2048;

// fp32 -> bf16 bits, round-to-nearest-even
DEV short f2bf(float f) {
  union { float f; unsigned u; } x; x.f = f;
  unsigned r = x.u + 0x7fffu + ((x.u >> 16) & 1u);
  return (short)(r >> 16);
}

// v_cvt_pk_bf16_f32 PROVEN exactly RNE on gfx950 (r10 vs r11 bit-identical).
DEV int cvtpk(float a, float b) {   // low word = bf16(a), high word = bf16(b)
  int r; asm("v_cvt_pk_bf16_f32 %0, %1, %2" : "=v"(r) : "v"(a), "v"(b)); return r;
}

DEV float fexp2(float x) { float r; asm("v_exp_f32 %0, %1" : "=v"(r) : "v"(x)); return r; }

#define MFMA16(a,b,c) __builtin_amdgcn_mfma_f32_16x16x32_bf16((a),(b),(c),0,0,0)
#define MFMA32(a,b,c) __builtin_amdgcn_mfma_f32_32x32x16_bf16((a),(b),(c),0,0,0)
// NOTE: imm-offset arg of global_load_lds applies to the LDS destination
// (round-7 failure). Always pass 0 and do explicit pointer arithmetic.
#define GLDS(g,l) __builtin_amdgcn_global_load_lds( \
    (const __attribute__((address_space(1))) void*)(g), \
    (__attribute__((address_space(3))) void*)(l), 16, 0, 0)
#define SBAR0() __builtin_amdgcn_sched_barrier(0)
#define ZERO16 {0,0,0,0,0,0,0,0,0,0,0,0,0,0,0,0}
#define ROT3(x) ((x) == 2 ? 0 : (x) + 1)

// NUMERICS RULE (r10/r11): reference quantizes Q on the UNSCALED bf16 grid.
// Round Q unscaled; apply log2(e)/32 in fp32 inside attention.
// SYNC RULES: (r20/r21) cross-wave DMA (GLDS) drained by its issuing wave
// BEFORE the publishing barrier. (r22) vmcnt is FIFO — to give stream X more
// slack than stream Y, X must be issued AFTER Y in the queue; r20's 2-deep
// prefetch failed because A was older than B so draining B force-drained A.

// ---------------------------------------------------------------- convert (weights only)
struct CvtArgs { const float* src[4]; short* dst[4]; int n[4]; };

__global__ void cvt_bf16(CvtArgs a) {
  const int task = blockIdx.y;
  const int i = (blockIdx.x * 256 + threadIdx.x) * 8;
  if (i >= a.n[task]) return;
  const float4v* s = (const float4v*)(a.src[task] + i);
  float4v x = s[0], y = s[1];
  bf16x8 o;
  o[0] = f2bf(x[0]); o[1] = f2bf(x[1]); o[2] = f2bf(x[2]); o[3] = f2bf(x[3]);
  o[4] = f2bf(y[0]); o[5] = f2bf(y[1]); o[6] = f2bf(y[2]); o[7] = f2bf(y[3]);
  *(bf16x8*)(a.dst[task] + i) = o;
}

// ---------------------------------------------------------------- mask bitpack
__global__ void maskpack(const int* __restrict__ m, unsigned long long* __restrict__ out) {
  const int gw = (blockIdx.x * 256 + threadIdx.x) >> 6;
  const int l  = threadIdx.x & 63;
  const int n = gw >> 16, kvblk = (gw >> 11) & 31, q = gw & 2047;
  int v = m[((size_t)n * SEQ + q) * SEQ + kvblk * 64 + l];
  unsigned long long b = __ballot(v != 0);
  if (l == 0) out[((size_t)n * 32 + kvblk) * SEQ + q] = b;
}

// ---------------------------------------------------------------- QKV GEMM core
// C = A @ B^T, A fp32 activations, B bf16 weights. A reg-staged 2-DEEP
// (sets X/Y, parity-static) with in-flight cvtpk (exact RNE); B via GLDS.
// Triple-buffer ring, 1 barrier/iter. QUEUE ORDER (r22): B issued BEFORE A
// each body, so the end-of-body drain of B(t+1) leaves A(t+3) in flight —
// true 2-body A slack. Body t: cvt+write A(t+1) (set (t&1)); issue B(t+2)
// GLDS; issue A(t+3) into same set; MFMA buf t%3; drain vmcnt(10)+lgkmcnt(0)
// [queue = B(t+1)2,A(t+2)4,B(t+2)2,A(t+3)4]; barrier.
// Tails: t=29 vmcnt(6), t=30 vmcnt(0), t=31 none.
template<int MODE>
DEV void gemm_qkv_core(const int vv, const float* __restrict__ A, const short* __restrict__ B,
                       short* __restrict__ Cb, short* As, short* Bs)
{
  const int t = threadIdx.x;
  const int l = t & 63, w = t >> 6;
  const int lr = l & 15, lh = l >> 4;
  const int m0 = (vv >> 3) * 128, n0 = (vv & 7) * 128;
  const int wr = w >> 1, wc = w & 1;
  f32x4 acc[4][4] = {};

  const int rA = t >> 2, cA = (t & 3) * 8;
  const float* gA  = A + (size_t)(m0 + rA) * 1024 + cA;
  const float* gA2 = gA + (size_t)64 * 1024;
  const short* gB  = B + (size_t)(n0 + rA) * 1024 + cA;
  const short* gB2 = gB + (size_t)64 * 1024;

  short* wA  = As + t * 8;          // row-major [128][32] per buffer
  short* wA2 = As + 2048 + t * 8;

  float4v x0, x1, x2, x3, y0, y1, y2, y3;

  // ---- prologue: A(0) sync stage -> buf0; then queue A(1),B(0),B(1),A(2)
  x0 = *(const float4v*)(gA);
  x1 = *(const float4v*)(gA + 4);
  x2 = *(const float4v*)(gA2);
  x3 = *(const float4v*)(gA2 + 4);
  {
    union { int w4[4]; bf16x8 v; } u1, u2;
    u1.w4[0] = cvtpk(x0[0], x0[1]); u1.w4[1] = cvtpk(x0[2], x0[3]);
    u1.w4[2] = cvtpk(x1[0], x1[1]); u1.w4[3] = cvtpk(x1[2], x1[3]);
    u2.w4[0] = cvtpk(x2[0], x2[1]); u2.w4[1] = cvtpk(x2[2], x2[3]);
    u2.w4[2] = cvtpk(x3[0], x3[1]); u2.w4[3] = cvtpk(x3[2], x3[3]);
    *(bf16x8*)(wA)  = u1.v;
    *(bf16x8*)(wA2) = u2.v;
  }
  SBAR0();
  x0 = *(const float4v*)(gA + 32);       // set X = A(1)
  x1 = *(const float4v*)(gA + 36);
  x2 = *(const float4v*)(gA2 + 32);
  x3 = *(const float4v*)(gA2 + 36);
  SBAR0();
  GLDS(gB,       Bs + w * 512);          // B(0)
  GLDS(gB2,      Bs + 2048 + w * 512);
  SBAR0();
  GLDS(gB + 32,  Bs + 4096 + w * 512);   // B(1)
  GLDS(gB2 + 32, Bs + 4096 + 2048 + w * 512);
  SBAR0();
  y0 = *(const float4v*)(gA + 64);       // set Y = A(2)
  y1 = *(const float4v*)(gA + 68);
  y2 = *(const float4v*)(gA2 + 64);
  y3 = *(const float4v*)(gA2 + 68);
  SBAR0();
  // drain A(1)+B(0) (oldest 6 of 12); A(0) ds_writes visible
  asm volatile("s_waitcnt vmcnt(6) lgkmcnt(0)" ::: "memory");
  SBAR0();
  __builtin_amdgcn_s_barrier();
  SBAR0();

  int cb = 0, sbA = 1, sbB = 2;
  #pragma unroll 1
  for (int it = 0; it < 32; ++it) {
    // ---- cvt + ds_write A(it+1) into buf sbA (set parity it&1)
    if (it < 31) {
      union { int w4[4]; bf16x8 v; } u1, u2;
      if ((it & 1) == 0) {
        u1.w4[0] = cvtpk(x0[0], x0[1]); u1.w4[1] = cvtpk(x0[2], x0[3]);
        u1.w4[2] = cvtpk(x1[0], x1[1]); u1.w4[3] = cvtpk(x1[2], x1[3]);
        u2.w4[0] = cvtpk(x2[0], x2[1]); u2.w4[1] = cvtpk(x2[2], x2[3]);
        u2.w4[2] = cvtpk(x3[0], x3[1]); u2.w4[3] = cvtpk(x3[2], x3[3]);
      } else {
        u1.w4[0] = cvtpk(y0[0], y0[1]); u1.w4[1] = cvtpk(y0[2], y0[3]);
        u1.w4[2] = cvtpk(y1[0], y1[1]); u1.w4[3] = cvtpk(y1[2], y1[3]);
        u2.w4[0] = cvtpk(y2[0], y2[1]); u2.w4[1] = cvtpk(y2[2], y2[3]);
        u2.w4[2] = cvtpk(y3[0], y3[1]); u2.w4[3] = cvtpk(y3[2], y3[3]);
      }
      *(bf16x8*)(wA  + sbA * 4096) = u1.v;
      *(bf16x8*)(wA2 + sbA * 4096) = u2.v;
      SBAR0();
    }
    // ---- issue B(it+2) GLDS FIRST (older in queue than A(it+3))
    if (it < 30) {
      const int kt = (it + 2) * 32;
      GLDS(gB + kt,  Bs + sbB * 4096 + w * 512);
      GLDS(gB2 + kt, Bs + sbB * 4096 + 2048 + w * 512);
      SBAR0();
    }
    // ---- issue A(it+3) into the just-consumed set (2-body slack)
    if (it < 29) {
      const int kt3 = (it + 3) * 32;
      if ((it & 1) == 0) {
        x0 = *(const float4v*)(gA + kt3);
        x1 = *(const float4v*)(gA + kt3 + 4);
        x2 = *(const float4v*)(gA2 + kt3);
        x3 = *(const float4v*)(gA2 + kt3 + 4);
      } else {
        y0 = *(const float4v*)(gA + kt3);
        y1 = *(const float4v*)(gA + kt3 + 4);
        y2 = *(const float4v*)(gA2 + kt3);
        y3 = *(const float4v*)(gA2 + kt3 + 4);
      }
      SBAR0();
    }
    // ---- MFMA on buf cb
    const short* as = As + cb * 4096;
    const short* bs = Bs + cb * 4096;
    bf16x8 af[4], bq[4];
    #pragma unroll
    for (int i = 0; i < 4; ++i)
      af[i] = *(const bf16x8*)&as[(wr * 64 + i * 16 + lr) * 32 + lh * 8];
    #pragma unroll
    for (int i = 0; i < 4; ++i)
      bq[i] = *(const bf16x8*)&bs[(wc * 64 + i * 16 + lr) * 32 + lh * 8];
    #pragma unroll
    for (int mi = 0; mi < 4; ++mi)
      #pragma unroll
      for (int ni = 0; ni < 4; ++ni)
        acc[mi][ni] = MFMA16(af[mi], bq[ni], acc[mi][ni]);

    // ---- end-of-iter: drain own B(it+1) DMA BEFORE barrier (airtight);
    //      A(it+2)/A(it+3) stay in flight (newer than B(it+1))
    SBAR0();
    if (it < 29)       { asm volatile("s_waitcnt vmcnt(10) lgkmcnt(0)" ::: "memory"); }
    else if (it == 29) { asm volatile("s_waitcnt vmcnt(6) lgkmcnt(0)" ::: "memory"); }
    else if (it == 30) { asm volatile("s_waitcnt vmcnt(0) lgkmcnt(0)" ::: "memory"); }
    if (it < 31) {
      SBAR0();
      __builtin_amdgcn_s_barrier();
      SBAR0();
    }
    cb = ROT3(cb); sbA = ROT3(sbA); sbB = ROT3(sbB);
  }

  #pragma unroll
  for (int mi = 0; mi < 4; ++mi)
    #pragma unroll
    for (int ni = 0; ni < 4; ++ni)
      #pragma unroll
      for (int r = 0; r < 4; ++r) {
        const int m = m0 + wr * 64 + mi * 16 + lh * 4 + r;
        const int e = n0 + wc * 64 + ni * 16 + lr;
        const float v = acc[mi][ni][r];
        const int nb = m >> 11, s = m & 2047, hh = e >> 6, d = e & 63;
        if (MODE == 0) {
          Cb[(((size_t)(nb * HEADS + hh)) * SEQ + s) * 64 + d] = f2bf(v);
        } else if (MODE == 2) {
          Cb[(((size_t)(nb * HEADS + hh)) * SEQ + s) * 64 + (d ^ ((s & 7) << 3))] = f2bf(v);
        } else {
          Cb[(((size_t)(nb * HEADS + hh)) * 32 + (s >> 6)) * 4096 + d * 64 +
             ((s & 63) ^ ((d & 7) << 3))] = f2bf(v);
        }
      }
}

// Q/K/V projections fused: grid 768 = 3 blocks/CU, one dispatch wave.
__global__ __launch_bounds__(256, 3)
void gemm_qkv(const float* __restrict__ Aq, const float* __restrict__ Ak,
              const float* __restrict__ Av, const short* __restrict__ Bb,
              short* __restrict__ Qp, short* __restrict__ Kp, short* __restrict__ VTp)
{
  __shared__ short As[3][4096];
  __shared__ short Bs[3][4096];
  const int lin = blockIdx.x;
  const int s = lin >> 8, j = lin & 255;
  const int vv = (j & 7) * 32 + (j >> 3);
  const short* B = Bb + (size_t)s * 1048576;   // wqb/wkb/wvb stride 2 MiB
  if (s == 0)      gemm_qkv_core<0>(vv, Aq, B, Qp,  &As[0][0], &Bs[0][0]);
  else if (s == 1) gemm_qkv_core<2>(vv, Ak, B, Kp,  &As[0][0], &Bs[0][0]);
  else             gemm_qkv_core<3>(vv, Av, B, VTp, &As[0][0], &Bs[0][0]);
}

// ---------------------------------------------------------------- output GEMM
// r18-proven: M-tile 64, grid 512 = 2 blocks/CU, vmcnt(3) triple-buffer ring.
__global__ __launch_bounds__(256, 2)
void gemm_out(const short* __restrict__ A, const short* __restrict__ B,
              float* __restrict__ Cf, const float* __restrict__ bias)
{
  __shared__ short AsArr[3][2048];
  __shared__ short BsArr[3][4096];
  short* As = &AsArr[0][0];
  short* Bs = &BsArr[0][0];
  const int lin = blockIdx.x;                   // [0,512)
  const int vv = (lin & 7) * 64 + (lin >> 3);   // xcd-chunked
  const int t = threadIdx.x;
  const int l = t & 63, w = t >> 6;
  const int lr = l & 15, lh = l >> 4;
  const int m0 = (vv >> 3) * 64, n0 = (vv & 7) * 128;
  const int wr = w >> 1, wc = w & 1;
  f32x4 acc[2][4] = {};

  const int rA = t >> 2, cA = (t & 3) * 8;      // rows 0..63
  const short* gA  = A + (size_t)(m0 + rA) * 1024 + cA;
  const short* gB  = B + (size_t)(n0 + rA) * 1024 + cA;
  const short* gB2 = gB + (size_t)64 * 1024;

  GLDS(gA,       As + w * 512);
  GLDS(gB,       Bs + w * 512);
  GLDS(gB2,      Bs + 2048 + w * 512);
  SBAR0();
  GLDS(gA + 32,  As + 2048 + w * 512);
  GLDS(gB + 32,  Bs + 4096 + w * 512);
  GLDS(gB2 + 32, Bs + 4096 + 2048 + w * 512);
  SBAR0();

  int cb = 0, sb = 2;
  #pragma unroll 1
  for (int it = 0; it < 32; ++it) {
    if (it < 31) { asm volatile("s_waitcnt vmcnt(3)" ::: "memory"); }
    else         { asm volatile("s_waitcnt vmcnt(0)" ::: "memory"); }
    SBAR0();
    __builtin_amdgcn_s_barrier();
    SBAR0();
    if (it < 30) {
      const int kt = (it + 2) * 32;
      GLDS(gA + kt,  As + sb * 2048 + w * 512);
      GLDS(gB + kt,  Bs + sb * 4096 + w * 512);
      GLDS(gB2 + kt, Bs + sb * 4096 + 2048 + w * 512);
      SBAR0();
    }

    const short* as = As + cb * 2048;
    const short* bs = Bs + cb * 4096;
    bf16x8 af[2], bq[4];
    #pragma unroll
    for (int i = 0; i < 2; ++i)
      af[i] = *(const bf16x8*)&as[(wr * 32 + i * 16 + lr) * 32 + lh * 8];
    #pragma unroll
    for (int i = 0; i < 4; ++i)
      bq[i] = *(const bf16x8*)&bs[(wc * 64 + i * 16 + lr) * 32 + lh * 8];
    #pragma unroll
    for (int mi = 0; mi < 2; ++mi)
      #pragma unroll
      for (int ni = 0; ni < 4; ++ni)
        acc[mi][ni] = MFMA16(af[mi], bq[ni], acc[mi][ni]);

    SBAR0();   // REQUIRED: no ds_read sinks past the next barrier (WAR)
    cb = ROT3(cb); sb = ROT3(sb);
  }

  #pragma unroll
  for (int mi = 0; mi < 2; ++mi)
    #pragma unroll
    for (int ni = 0; ni < 4; ++ni)
      #pragma unroll
      for (int r = 0; r < 4; ++r) {
        const int m = m0 + wr * 32 + mi * 16 + lh * 4 + r;
        const int e = n0 + wc * 64 + ni * 16 + lr;
        Cf[(size_t)m * EMBED + e] = acc[mi][ni][r] + bias[e];
      }
}

// ---------------------------------------------------------------- attention
// r13-proven single-kernel form (65.0us, absmax 9.77e-4). Grid 512 = 2/CU.
__global__ __launch_bounds__(256, 2)
void attn256(const short* __restrict__ Qp, const short* __restrict__ Kp,
             const short* __restrict__ VTp, const unsigned long long* __restrict__ MbT,
             short* __restrict__ Aout)
{
  __shared__ short lds[2][8192];   // per buf: K tile 4096 shorts | VT tile 4096 shorts

  const int t = threadIdx.x, l = t & 63, w = t >> 6;   // w: 0..3
  const int lq = l & 31, hi = l >> 5;
  const int lin = blockIdx.x;
  const int vv = (lin & 7) * 64 + (lin >> 3);   // [0,512)
  const int hl = vv >> 4, qb = vv & 15;
  const int n = hl >> 4, h = hl & 15;
  const int q0 = qb * 128;
  const int myq = q0 + w * 32 + lq;
  const size_t hb = (size_t)(n * HEADS + h) * SEQ * 64;
  const short* Qh = Qp + hb;
  const float SCL = 0.045084220027780106f;   // log2(e)/32 — fp32, applied here

  // Q fragments (B-operand), resident all block
  bf16x8 qf[4];
  #pragma unroll
  for (int ks = 0; ks < 4; ++ks)
    qf[ks] = *(const bf16x8*)(Qh + (size_t)myq * 64 + ks * 16 + hi * 8);

  const short ONE = (short)0x3F80;
  const bf16x8 onesv = {ONE, ONE, ONE, ONE, ONE, ONE, ONE, ONE};
  const f32x16 zerov = ZERO16;

  f32x16 acco[2] = { ZERO16, ZERO16 };
  f32x16 accl = ZERO16;   // denominator accumulator (all regs = q-row sum)

  const short* kgp = Kp + hb + w * 1024 + l * 8;
  const short* vgp = VTp + hb + w * 1024 + l * 8;
  const unsigned long long* mp = MbT + (size_t)n * (32 * SEQ) + myq;

  // prologue: mask word + stage tile 0 into buf 0 (per-lane src: + l*8)
  unsigned long long mw = *mp; mp += SEQ;
  {
    GLDS(kgp,       &lds[0][w * 1024]);
    GLDS(kgp + 512, &lds[0][w * 1024 + 512]);
    GLDS(vgp,       &lds[0][4096 + w * 1024]);
    GLDS(vgp + 512, &lds[0][4096 + w * 1024 + 512]);
    kgp += 4096; vgp += 4096;
  }

  #pragma unroll 1
  for (int tt = 0; tt < 32; ++tt) {
    unsigned long long mw_next = 0;
    if (tt < 31) {
      mw_next = *mp; mp += SEQ;
      SBAR0();   // lock queue order: mask load precedes the GLDS quad
      const int nb = (tt + 1) & 1;
      GLDS(kgp,       &lds[nb][w * 1024]);
      GLDS(kgp + 512, &lds[nb][w * 1024 + 512]);
      GLDS(vgp,       &lds[nb][4096 + w * 1024]);
      GLDS(vgp + 512, &lds[nb][4096 + w * 1024 + 512]);
      kgp += 4096; vgp += 4096;
      asm volatile("s_waitcnt vmcnt(5)" ::: "memory");
      SBAR0();
    } else {
      asm volatile("s_waitcnt vmcnt(0)" ::: "memory");
      SBAR0();
    }
    __builtin_amdgcn_s_barrier();
    SBAR0();   // no ds_read hoists above the staging barrier

    const short* Ks  = &lds[tt & 1][0];
    const short* VTs = &lds[tt & 1][4096];

    #pragma unroll
    for (int half = 0; half < 2; ++half) {
      // ---- S^T[32kv][32q] over d=64: A = K rows, B = Q (reg); C0 = zerov
      f32x16 sacc;
      __builtin_amdgcn_s_setprio(1);
      #pragma unroll
      for (int ks = 0; ks < 4; ++ks) {
        const int d = ks * 16 + hi * 8;
        bf16x8 kf = *(const bf16x8*)&Ks[(half * 32 + lq) * 64 + (d ^ ((lq & 7) << 3))];
        sacc = MFMA32(kf, qf[ks], ks == 0 ? zerov : sacc);
      }
      __builtin_amdgcn_s_setprio(0);
      // ---- p = exp2(fma(sacc, SCL, bias)); bias = -200 where masked
      const unsigned mmw = ~(unsigned)(mw >> (half * 32 + hi * 4));
      float p[16];
      #pragma unroll
      for (int r = 0; r < 16; ++r) {
        const int idx = (r & 3) + 8 * (r >> 2);
        union { int i; float f; } b;
        b.i = __builtin_amdgcn_sbfe(mmw, idx, 1) & 0xC3480000;   // 0 or -200.0f
        p[r] = fexp2(__builtin_fmaf(sacc[r], SCL, b.f));
      }
      // ---- P^T B-fragments: 4 cvt_pk + 2 permlane32_swap per 16-kv step
      bf16x8 pf[2];
      #pragma unroll
      for (int kb = 0; kb < 2; ++kb) {
        int x1 = cvtpk(p[kb * 8 + 0], p[kb * 8 + 1]);
        int y1 = cvtpk(p[kb * 8 + 4], p[kb * 8 + 5]);
        int x2 = cvtpk(p[kb * 8 + 2], p[kb * 8 + 3]);
        int y2 = cvtpk(p[kb * 8 + 6], p[kb * 8 + 7]);
        asm("v_permlane32_swap_b32 %0, %1" : "+v"(x1), "+v"(y1));
        asm("v_permlane32_swap_b32 %0, %1" : "+v"(x2), "+v"(y2));
        union { int w4[4]; bf16x8 v; } u;
        u.w4[0] = x1; u.w4[1] = x2; u.w4[2] = y1; u.w4[3] = y2;
        pf[kb] = u.v;
      }
      // ---- O^T += V^T . P^T ; denominator accl += ones . P^T (MFMA pipe)
      __builtin_amdgcn_s_setprio(1);
      accl = MFMA32(onesv, pf[0], accl);
      accl = MFMA32(onesv, pf[1], accl);
      #pragma unroll
      for (int dt = 0; dt < 2; ++dt) {
        const int d = dt * 32 + lq;
        #pragma unroll
        for (int kb = 0; kb < 2; ++kb) {
          const int kv = half * 32 + kb * 16 + hi * 8;
          bf16x8 vf = *(const bf16x8*)&VTs[d * 64 + (kv ^ ((d & 7) << 3))];
          acco[dt] = MFMA32(vf, pf[kb], acco[dt]);
        }
      }
      __builtin_amdgcn_s_setprio(0);
    }
    mw = mw_next;
    SBAR0();   // no ds_read of buf[tt&1] sinks below the end-of-iter barrier
    __builtin_amdgcn_s_barrier();
    SBAR0();
  }

  // ---- epilogue: scale by 1/rowsum (accl: every reg = q-row sum), store bf16
  const float invs = 1.f / (accl[0] + 1e-30f);

  short* ot = &lds[0][0] + w * 2048;   // wave-private 32q x 64d (swizzled)
  #pragma unroll
  for (int dt = 0; dt < 2; ++dt)
    #pragma unroll
    for (int r = 0; r < 16; ++r) {
      const int d = dt * 32 + (r & 3) + 8 * (r >> 2) + 4 * hi;
      ot[lq * 64 + (d ^ ((lq & 7) << 3))] = f2bf(acco[dt][r] * invs);
    }
  __syncthreads();

  const int qq = l >> 1, hb2 = l & 1;
  #pragma unroll
  for (int it = 0; it < 4; ++it) {
    const int didx = (hb2 * 32 + it * 8) ^ ((qq & 7) << 3);
    bf16x8 v = *(const bf16x8*)&ot[qq * 64 + didx];
    *(bf16x8*)&Aout[((size_t)(n * SEQ + q0 + w * 32 + qq)) * EMBED + h * 64 + hb2 * 32 + it * 8] = v;
  }
}

// ---------------------------------------------------------------- launcher
extern "C" void kernel_launch(void* const* d_in, const int* in_sizes, int n_in,
                              void* d_out, int out_size, void* d_ws, size_t ws_size,
                              hipStream_t stream) {
  (void)in_sizes; (void)n_in; (void)out_size;
  const float* queries = (const float*)d_in[0];
  const float* keys    = (const float*)d_in[1];
  const float* values  = (const float*)d_in[2];
  const int*   mask    = (const int*)d_in[3];
  const float* Wq      = (const float*)d_in[4];
  const float* Wk      = (const float*)d_in[5];
  const float* Wv      = (const float*)d_in[6];
  const float* Wo      = (const float*)d_in[7];
  const float* bo      = (const float*)d_in[8];

  const size_t NEED = (size_t)76 * 1024 * 1024;
  if (ws_size < NEED) return;

  char* ws = (char*)d_ws;
  short* wqb  = (short*)(ws + (24u << 20)); // weights, stride 2 MiB
  short* wob  = (short*)(ws + (30u << 20));
  unsigned long long* mbits = (unsigned long long*)(ws + (32u << 20)); // 1 MiB
  short* Qp   = (short*)(ws + (40u << 20));
  short* Kp   = (short*)(ws + (48u << 20));
  short* VTp  = (short*)(ws + (56u << 20));
  short* ao   = (short*)(ws + (64u << 20));

  const int NW = EMBED * EMBED;

  CvtArgs ca;
  ca.src[0] = Wq; ca.dst[0] = wqb;                         ca.n[0] = NW;
  ca.src[1] = Wk; ca.dst[1] = (short*)(ws + (26u << 20));  ca.n[1] = NW;
  ca.src[2] = Wv; ca.dst[2] = (short*)(ws + (28u << 20));  ca.n[2] = NW;
  ca.src[3] = Wo; ca.dst[3] = wob;                         ca.n[3] = NW;
  cvt_bf16<<<dim3(512, 4), 256, 0, stream>>>(ca);

  maskpack<<<dim3(32768), 256, 0, stream>>>(mask, mbits);

  gemm_qkv<<<dim3(768), 256, 0, stream>>>(queries, keys, values, wqb, Qp, Kp, VTp);

  attn256<<<dim3(512), 256, 0, stream>>>(Qp, Kp, VTp, mbits, ao);

  gemm_out<<<dim3(512), 256, 0, stream>>>(ao, wob, (float*)d_out, bo);
}

// Round 23
// 137.239 us; speedup vs baseline: 1.0541x; 1.0541x over previous
//
#include <hip/hip_runtime.h>
#include <stdint.h>
#include <stddef.h>

typedef __attribute__((ext_vector_type(8)))  short bf16x8;
typedef __attribute__((ext_vector_type(2)))  float f32x2;
typedef __attribute__((ext_vector_type(4)))  float f32x4;
typedef __attribute__((ext_vector_type(16))) float f32x16;
typedef __attribute__((ext_vector_type(4)))  float float4v;
typedef __attribute__((ext_vector_type(4)))  int   int4v;

#define DEV static __device__ __forceinline__

static constexpr int EMBED  = 1024;
static constexpr int HEADS  = 16;
static constexpr int SEQ    = 2048;

// fp32 -> bf16 bits, round-to-nearest-even
DEV short f2bf(float f) {
  union { float f; unsigned u; } x; x.f = f;
  unsigned r = x.u + 0x7fffu + ((x.u >> 16) & 1u);
  return (short)(r >> 16);
}

// v_cvt_pk_bf16_f32 PROVEN exactly RNE on gfx950 (r10 vs r11 bit-identical).
DEV int cvtpk(float a, float b) {   // low word = bf16(a), high word = bf16(b)
  int r; asm("v_cvt_pk_bf16_f32 %0, %1, %2" : "=v"(r) : "v"(a), "v"(b)); return r;
}

DEV float fexp2(float x) { float r; asm("v_exp_f32 %0, %1" : "=v"(r) : "v"(x)); return r; }

#define MFMA16(a,b,c) __builtin_amdgcn_mfma_f32_16x16x32_bf16((a),(b),(c),0,0,0)
#define MFMA32(a,b,c) __builtin_amdgcn_mfma_f32_32x32x16_bf16((a),(b),(c),0,0,0)
// NOTE: imm-offset arg of global_load_lds applies to the LDS destination
// (round-7 failure). Always pass 0 and do explicit pointer arithmetic.
#define GLDS(g,l) __builtin_amdgcn_global_load_lds( \
    (const __attribute__((address_space(1))) void*)(g), \
    (__attribute__((address_space(3))) void*)(l), 16, 0, 0)
#define SBAR0() __builtin_amdgcn_sched_barrier(0)
#define ZERO16 {0,0,0,0,0,0,0,0,0,0,0,0,0,0,0,0}
#define ROT3(x) ((x) == 2 ? 0 : (x) + 1)

// NUMERICS RULE (r10/r11): reference quantizes Q on the UNSCALED bf16 grid.
// Round Q unscaled; apply log2(e)/32 in fp32 inside attention.
// SYNC RULES: (r20/r21) cross-wave DMA (GLDS) drained by its issuing wave
// BEFORE the publishing barrier. Per-wave register loads need no manual
// drain (compiler inserts the vmcnt at the use site).
// PLATEAUS: attn ~65us (4 structural variants); qkv ~67us in this 1-deep
// form (2-deep regressed twice: r20 +9us, r22 +7us). This file = r21,
// the measured session best (137.3us).

// ---------------------------------------------------------------- convert (weights only)
struct CvtArgs { const float* src[4]; short* dst[4]; int n[4]; };

__global__ void cvt_bf16(CvtArgs a) {
  const int task = blockIdx.y;
  const int i = (blockIdx.x * 256 + threadIdx.x) * 8;
  if (i >= a.n[task]) return;
  const float4v* s = (const float4v*)(a.src[task] + i);
  float4v x = s[0], y = s[1];
  bf16x8 o;
  o[0] = f2bf(x[0]); o[1] = f2bf(x[1]); o[2] = f2bf(x[2]); o[3] = f2bf(x[3]);
  o[4] = f2bf(y[0]); o[5] = f2bf(y[1]); o[6] = f2bf(y[2]); o[7] = f2bf(y[3]);
  *(bf16x8*)(a.dst[task] + i) = o;
}

// ---------------------------------------------------------------- mask bitpack
__global__ void maskpack(const int* __restrict__ m, unsigned long long* __restrict__ out) {
  const int gw = (blockIdx.x * 256 + threadIdx.x) >> 6;
  const int l  = threadIdx.x & 63;
  const int n = gw >> 16, kvblk = (gw >> 11) & 31, q = gw & 2047;
  int v = m[((size_t)n * SEQ + q) * SEQ + kvblk * 64 + l];
  unsigned long long b = __ballot(v != 0);
  if (l == 0) out[((size_t)n * 32 + kvblk) * SEQ + q] = b;
}

// ---------------------------------------------------------------- QKV GEMM core
// C = A @ B^T, A fp32 activations, B bf16 weights. A reg-staged 1-deep with
// in-flight cvtpk (exact RNE); B via GLDS. Triple-buffer ring, 1 barrier/iter.
// Body t: cvt+write A(t+1) -> buf (t+1)%3; issue A(t+2) reg-loads + B(t+2)
// GLDS; MFMA buf t%3; END: vmcnt(6) drains B(t+1) ONLY (queue =
// [B(t+1)x2, A(t+2)x4, B(t+2)x2]) + lgkmcnt(0); barrier. A-loads drained by
// compiler at their cvt use site. Tails: t=30 vmcnt(0); t=31 none.
template<int MODE>
DEV void gemm_qkv_core(const int vv, const float* __restrict__ A, const short* __restrict__ B,
                       short* __restrict__ Cb, short* As, short* Bs)
{
  const int t = threadIdx.x;
  const int l = t & 63, w = t >> 6;
  const int lr = l & 15, lh = l >> 4;
  const int m0 = (vv >> 3) * 128, n0 = (vv & 7) * 128;
  const int wr = w >> 1, wc = w & 1;
  f32x4 acc[4][4] = {};

  const int rA = t >> 2, cA = (t & 3) * 8;
  const float* gA  = A + (size_t)(m0 + rA) * 1024 + cA;
  const float* gA2 = gA + (size_t)64 * 1024;
  const short* gB  = B + (size_t)(n0 + rA) * 1024 + cA;
  const short* gB2 = gB + (size_t)64 * 1024;

  short* wA  = As + t * 8;          // row-major [128][32] per buffer
  short* wA2 = As + 2048 + t * 8;

  // ---- prologue: A(0) sync stage -> buf0; regs = A(1); GLDS B(0),B(1)
  float4v a0 = *(const float4v*)(gA);
  float4v a1 = *(const float4v*)(gA + 4);
  float4v a2 = *(const float4v*)(gA2);
  float4v a3 = *(const float4v*)(gA2 + 4);
  {
    union { int w4[4]; bf16x8 v; } u1, u2;
    u1.w4[0] = cvtpk(a0[0], a0[1]); u1.w4[1] = cvtpk(a0[2], a0[3]);
    u1.w4[2] = cvtpk(a1[0], a1[1]); u1.w4[3] = cvtpk(a1[2], a1[3]);
    u2.w4[0] = cvtpk(a2[0], a2[1]); u2.w4[1] = cvtpk(a2[2], a2[3]);
    u2.w4[2] = cvtpk(a3[0], a3[1]); u2.w4[3] = cvtpk(a3[2], a3[3]);
    *(bf16x8*)(wA)  = u1.v;
    *(bf16x8*)(wA2) = u2.v;
  }
  SBAR0();
  a0 = *(const float4v*)(gA + 32);
  a1 = *(const float4v*)(gA + 36);
  a2 = *(const float4v*)(gA2 + 32);
  a3 = *(const float4v*)(gA2 + 36);
  SBAR0();
  GLDS(gB,       Bs + w * 512);
  GLDS(gB2,      Bs + 2048 + w * 512);
  GLDS(gB + 32,  Bs + 4096 + w * 512);
  GLDS(gB2 + 32, Bs + 4096 + 2048 + w * 512);
  SBAR0();
  // drain B(0) (leave B(1) in flight; A(1) regs handled by compiler at use)
  asm volatile("s_waitcnt vmcnt(2) lgkmcnt(0)" ::: "memory");
  SBAR0();
  __builtin_amdgcn_s_barrier();
  SBAR0();

  int cb = 0, sbA = 1, sbB = 2;
  #pragma unroll 1
  for (int it = 0; it < 32; ++it) {
    // ---- cvt + ds_write A(it+1) into buf sbA (compiler drains a-regs here)
    if (it < 31) {
      union { int w4[4]; bf16x8 v; } u1, u2;
      u1.w4[0] = cvtpk(a0[0], a0[1]); u1.w4[1] = cvtpk(a0[2], a0[3]);
      u1.w4[2] = cvtpk(a1[0], a1[1]); u1.w4[3] = cvtpk(a1[2], a1[3]);
      u2.w4[0] = cvtpk(a2[0], a2[1]); u2.w4[1] = cvtpk(a2[2], a2[3]);
      u2.w4[2] = cvtpk(a3[0], a3[1]); u2.w4[3] = cvtpk(a3[2], a3[3]);
      *(bf16x8*)(wA  + sbA * 4096) = u1.v;
      *(bf16x8*)(wA2 + sbA * 4096) = u2.v;
      SBAR0();
    }
    // ---- issue A(it+2) reg-loads + B(it+2) GLDS
    if (it < 30) {
      const int kt = (it + 2) * 32;
      a0 = *(const float4v*)(gA + kt);
      a1 = *(const float4v*)(gA + kt + 4);
      a2 = *(const float4v*)(gA2 + kt);
      a3 = *(const float4v*)(gA2 + kt + 4);
      GLDS(gB + kt,  Bs + sbB * 4096 + w * 512);
      GLDS(gB2 + kt, Bs + sbB * 4096 + 2048 + w * 512);
      SBAR0();
    }
    // ---- MFMA on buf cb
    const short* as = As + cb * 4096;
    const short* bs = Bs + cb * 4096;
    bf16x8 af[4], bq[4];
    #pragma unroll
    for (int i = 0; i < 4; ++i)
      af[i] = *(const bf16x8*)&as[(wr * 64 + i * 16 + lr) * 32 + lh * 8];
    #pragma unroll
    for (int i = 0; i < 4; ++i)
      bq[i] = *(const bf16x8*)&bs[(wc * 64 + i * 16 + lr) * 32 + lh * 8];
    #pragma unroll
    for (int mi = 0; mi < 4; ++mi)
      #pragma unroll
      for (int ni = 0; ni < 4; ++ni)
        acc[mi][ni] = MFMA16(af[mi], bq[ni], acc[mi][ni]);

    // ---- end-of-iter: drain own B(it+1) DMA BEFORE barrier (airtight)
    SBAR0();
    if (it < 30)       { asm volatile("s_waitcnt vmcnt(6) lgkmcnt(0)" ::: "memory"); }
    else if (it == 30) { asm volatile("s_waitcnt vmcnt(0) lgkmcnt(0)" ::: "memory"); }
    if (it < 31) {
      SBAR0();
      __builtin_amdgcn_s_barrier();
      SBAR0();
    }
    cb = ROT3(cb); sbA = ROT3(sbA); sbB = ROT3(sbB);
  }

  #pragma unroll
  for (int mi = 0; mi < 4; ++mi)
    #pragma unroll
    for (int ni = 0; ni < 4; ++ni)
      #pragma unroll
      for (int r = 0; r < 4; ++r) {
        const int m = m0 + wr * 64 + mi * 16 + lh * 4 + r;
        const int e = n0 + wc * 64 + ni * 16 + lr;
        const float v = acc[mi][ni][r];
        const int nb = m >> 11, s = m & 2047, hh = e >> 6, d = e & 63;
        if (MODE == 0) {
          Cb[(((size_t)(nb * HEADS + hh)) * SEQ + s) * 64 + d] = f2bf(v);
        } else if (MODE == 2) {
          Cb[(((size_t)(nb * HEADS + hh)) * SEQ + s) * 64 + (d ^ ((s & 7) << 3))] = f2bf(v);
        } else {
          Cb[(((size_t)(nb * HEADS + hh)) * 32 + (s >> 6)) * 4096 + d * 64 +
             ((s & 63) ^ ((d & 7) << 3))] = f2bf(v);
        }
      }
}

// Q/K/V projections fused: grid 768 = 3 blocks/CU, one dispatch wave.
__global__ __launch_bounds__(256, 3)
void gemm_qkv(const float* __restrict__ Aq, const float* __restrict__ Ak,
              const float* __restrict__ Av, const short* __restrict__ Bb,
              short* __restrict__ Qp, short* __restrict__ Kp, short* __restrict__ VTp)
{
  __shared__ short As[3][4096];
  __shared__ short Bs[3][4096];
  const int lin = blockIdx.x;
  const int s = lin >> 8, j = lin & 255;
  const int vv = (j & 7) * 32 + (j >> 3);
  const short* B = Bb + (size_t)s * 1048576;   // wqb/wkb/wvb stride 2 MiB
  if (s == 0)      gemm_qkv_core<0>(vv, Aq, B, Qp,  &As[0][0], &Bs[0][0]);
  else if (s == 1) gemm_qkv_core<2>(vv, Ak, B, Kp,  &As[0][0], &Bs[0][0]);
  else             gemm_qkv_core<3>(vv, Av, B, VTp, &As[0][0], &Bs[0][0]);
}

// ---------------------------------------------------------------- output GEMM
// r18-proven: M-tile 64, grid 512 = 2 blocks/CU, vmcnt(3) triple-buffer ring.
__global__ __launch_bounds__(256, 2)
void gemm_out(const short* __restrict__ A, const short* __restrict__ B,
              float* __restrict__ Cf, const float* __restrict__ bias)
{
  __shared__ short AsArr[3][2048];
  __shared__ short BsArr[3][4096];
  short* As = &AsArr[0][0];
  short* Bs = &BsArr[0][0];
  const int lin = blockIdx.x;                   // [0,512)
  const int vv = (lin & 7) * 64 + (lin >> 3);   // xcd-chunked
  const int t = threadIdx.x;
  const int l = t & 63, w = t >> 6;
  const int lr = l & 15, lh = l >> 4;
  const int m0 = (vv >> 3) * 64, n0 = (vv & 7) * 128;
  const int wr = w >> 1, wc = w & 1;
  f32x4 acc[2][4] = {};

  const int rA = t >> 2, cA = (t & 3) * 8;      // rows 0..63
  const short* gA  = A + (size_t)(m0 + rA) * 1024 + cA;
  const short* gB  = B + (size_t)(n0 + rA) * 1024 + cA;
  const short* gB2 = gB + (size_t)64 * 1024;

  GLDS(gA,       As + w * 512);
  GLDS(gB,       Bs + w * 512);
  GLDS(gB2,      Bs + 2048 + w * 512);
  SBAR0();
  GLDS(gA + 32,  As + 2048 + w * 512);
  GLDS(gB + 32,  Bs + 4096 + w * 512);
  GLDS(gB2 + 32, Bs + 4096 + 2048 + w * 512);
  SBAR0();

  int cb = 0, sb = 2;
  #pragma unroll 1
  for (int it = 0; it < 32; ++it) {
    if (it < 31) { asm volatile("s_waitcnt vmcnt(3)" ::: "memory"); }
    else         { asm volatile("s_waitcnt vmcnt(0)" ::: "memory"); }
    SBAR0();
    __builtin_amdgcn_s_barrier();
    SBAR0();
    if (it < 30) {
      const int kt = (it + 2) * 32;
      GLDS(gA + kt,  As + sb * 2048 + w * 512);
      GLDS(gB + kt,  Bs + sb * 4096 + w * 512);
      GLDS(gB2 + kt, Bs + sb * 4096 + 2048 + w * 512);
      SBAR0();
    }

    const short* as = As + cb * 2048;
    const short* bs = Bs + cb * 4096;
    bf16x8 af[2], bq[4];
    #pragma unroll
    for (int i = 0; i < 2; ++i)
      af[i] = *(const bf16x8*)&as[(wr * 32 + i * 16 + lr) * 32 + lh * 8];
    #pragma unroll
    for (int i = 0; i < 4; ++i)
      bq[i] = *(const bf16x8*)&bs[(wc * 64 + i * 16 + lr) * 32 + lh * 8];
    #pragma unroll
    for (int mi = 0; mi < 2; ++mi)
      #pragma unroll
      for (int ni = 0; ni < 4; ++ni)
        acc[mi][ni] = MFMA16(af[mi], bq[ni], acc[mi][ni]);

    SBAR0();   // REQUIRED: no ds_read sinks past the next barrier (WAR)
    cb = ROT3(cb); sb = ROT3(sb);
  }

  #pragma unroll
  for (int mi = 0; mi < 2; ++mi)
    #pragma unroll
    for (int ni = 0; ni < 4; ++ni)
      #pragma unroll
      for (int r = 0; r < 4; ++r) {
        const int m = m0 + wr * 32 + mi * 16 + lh * 4 + r;
        const int e = n0 + wc * 64 + ni * 16 + lr;
        Cf[(size_t)m * EMBED + e] = acc[mi][ni][r] + bias[e];
      }
}

// ---------------------------------------------------------------- attention
// r13-proven single-kernel form (65.0us, absmax 9.77e-4). Grid 512 = 2/CU.
__global__ __launch_bounds__(256, 2)
void attn256(const short* __restrict__ Qp, const short* __restrict__ Kp,
             const short* __restrict__ VTp, const unsigned long long* __restrict__ MbT,
             short* __restrict__ Aout)
{
  __shared__ short lds[2][8192];   // per buf: K tile 4096 shorts | VT tile 4096 shorts

  const int t = threadIdx.x, l = t & 63, w = t >> 6;   // w: 0..3
  const int lq = l & 31, hi = l >> 5;
  const int lin = blockIdx.x;
  const int vv = (lin & 7) * 64 + (lin >> 3);   // [0,512)
  const int hl = vv >> 4, qb = vv & 15;
  const int n = hl >> 4, h = hl & 15;
  const int q0 = qb * 128;
  const int myq = q0 + w * 32 + lq;
  const size_t hb = (size_t)(n * HEADS + h) * SEQ * 64;
  const short* Qh = Qp + hb;
  const float SCL = 0.045084220027780106f;   // log2(e)/32 — fp32, applied here

  // Q fragments (B-operand), resident all block
  bf16x8 qf[4];
  #pragma unroll
  for (int ks = 0; ks < 4; ++ks)
    qf[ks] = *(const bf16x8*)(Qh + (size_t)myq * 64 + ks * 16 + hi * 8);

  const short ONE = (short)0x3F80;
  const bf16x8 onesv = {ONE, ONE, ONE, ONE, ONE, ONE, ONE, ONE};
  const f32x16 zerov = ZERO16;

  f32x16 acco[2] = { ZERO16, ZERO16 };
  f32x16 accl = ZERO16;   // denominator accumulator (all regs = q-row sum)

  const short* kgp = Kp + hb + w * 1024 + l * 8;
  const short* vgp = VTp + hb + w * 1024 + l * 8;
  const unsigned long long* mp = MbT + (size_t)n * (32 * SEQ) + myq;

  // prologue: mask word + stage tile 0 into buf 0 (per-lane src: + l*8)
  unsigned long long mw = *mp; mp += SEQ;
  {
    GLDS(kgp,       &lds[0][w * 1024]);
    GLDS(kgp + 512, &lds[0][w * 1024 + 512]);
    GLDS(vgp,       &lds[0][4096 + w * 1024]);
    GLDS(vgp + 512, &lds[0][4096 + w * 1024 + 512]);
    kgp += 4096; vgp += 4096;
  }

  #pragma unroll 1
  for (int tt = 0; tt < 32; ++tt) {
    unsigned long long mw_next = 0;
    if (tt < 31) {
      mw_next = *mp; mp += SEQ;
      SBAR0();   // lock queue order: mask load precedes the GLDS quad
      const int nb = (tt + 1) & 1;
      GLDS(kgp,       &lds[nb][w * 1024]);
      GLDS(kgp + 512, &lds[nb][w * 1024 + 512]);
      GLDS(vgp,       &lds[nb][4096 + w * 1024]);
      GLDS(vgp + 512, &lds[nb][4096 + w * 1024 + 512]);
      kgp += 4096; vgp += 4096;
      asm volatile("s_waitcnt vmcnt(5)" ::: "memory");
      SBAR0();
    } else {
      asm volatile("s_waitcnt vmcnt(0)" ::: "memory");
      SBAR0();
    }
    __builtin_amdgcn_s_barrier();
    SBAR0();   // no ds_read hoists above the staging barrier

    const short* Ks  = &lds[tt & 1][0];
    const short* VTs = &lds[tt & 1][4096];

    #pragma unroll
    for (int half = 0; half < 2; ++half) {
      // ---- S^T[32kv][32q] over d=64: A = K rows, B = Q (reg); C0 = zerov
      f32x16 sacc;
      __builtin_amdgcn_s_setprio(1);
      #pragma unroll
      for (int ks = 0; ks < 4; ++ks) {
        const int d = ks * 16 + hi * 8;
        bf16x8 kf = *(const bf16x8*)&Ks[(half * 32 + lq) * 64 + (d ^ ((lq & 7) << 3))];
        sacc = MFMA32(kf, qf[ks], ks == 0 ? zerov : sacc);
      }
      __builtin_amdgcn_s_setprio(0);
      // ---- p = exp2(fma(sacc, SCL, bias)); bias = -200 where masked
      const unsigned mmw = ~(unsigned)(mw >> (half * 32 + hi * 4));
      float p[16];
      #pragma unroll
      for (int r = 0; r < 16; ++r) {
        const int idx = (r & 3) + 8 * (r >> 2);
        union { int i; float f; } b;
        b.i = __builtin_amdgcn_sbfe(mmw, idx, 1) & 0xC3480000;   // 0 or -200.0f
        p[r] = fexp2(__builtin_fmaf(sacc[r], SCL, b.f));
      }
      // ---- P^T B-fragments: 4 cvt_pk + 2 permlane32_swap per 16-kv step
      bf16x8 pf[2];
      #pragma unroll
      for (int kb = 0; kb < 2; ++kb) {
        int x1 = cvtpk(p[kb * 8 + 0], p[kb * 8 + 1]);
        int y1 = cvtpk(p[kb * 8 + 4], p[kb * 8 + 5]);
        int x2 = cvtpk(p[kb * 8 + 2], p[kb * 8 + 3]);
        int y2 = cvtpk(p[kb * 8 + 6], p[kb * 8 + 7]);
        asm("v_permlane32_swap_b32 %0, %1" : "+v"(x1), "+v"(y1));
        asm("v_permlane32_swap_b32 %0, %1" : "+v"(x2), "+v"(y2));
        union { int w4[4]; bf16x8 v; } u;
        u.w4[0] = x1; u.w4[1] = x2; u.w4[2] = y1; u.w4[3] = y2;
        pf[kb] = u.v;
      }
      // ---- O^T += V^T . P^T ; denominator accl += ones . P^T (MFMA pipe)
      __builtin_amdgcn_s_setprio(1);
      accl = MFMA32(onesv, pf[0], accl);
      accl = MFMA32(onesv, pf[1], accl);
      #pragma unroll
      for (int dt = 0; dt < 2; ++dt) {
        const int d = dt * 32 + lq;
        #pragma unroll
        for (int kb = 0; kb < 2; ++kb) {
          const int kv = half * 32 + kb * 16 + hi * 8;
          bf16x8 vf = *(const bf16x8*)&VTs[d * 64 + (kv ^ ((d & 7) << 3))];
          acco[dt] = MFMA32(vf, pf[kb], acco[dt]);
        }
      }
      __builtin_amdgcn_s_setprio(0);
    }
    mw = mw_next;
    SBAR0();   // no ds_read of buf[tt&1] sinks below the end-of-iter barrier
    __builtin_amdgcn_s_barrier();
    SBAR0();
  }

  // ---- epilogue: scale by 1/rowsum (accl: every reg = q-row sum), store bf16
  const float invs = 1.f / (accl[0] + 1e-30f);

  short* ot = &lds[0][0] + w * 2048;   // wave-private 32q x 64d (swizzled)
  #pragma unroll
  for (int dt = 0; dt < 2; ++dt)
    #pragma unroll
    for (int r = 0; r < 16; ++r) {
      const int d = dt * 32 + (r & 3) + 8 * (r >> 2) + 4 * hi;
      ot[lq * 64 + (d ^ ((lq & 7) << 3))] = f2bf(acco[dt][r] * invs);
    }
  __syncthreads();

  const int qq = l >> 1, hb2 = l & 1;
  #pragma unroll
  for (int it = 0; it < 4; ++it) {
    const int didx = (hb2 * 32 + it * 8) ^ ((qq & 7) << 3);
    bf16x8 v = *(const bf16x8*)&ot[qq * 64 + didx];
    *(bf16x8*)&Aout[((size_t)(n * SEQ + q0 + w * 32 + qq)) * EMBED + h * 64 + hb2 * 32 + it * 8] = v;
  }
}

// ---------------------------------------------------------------- launcher
extern "C" void kernel_launch(void* const* d_in, const int* in_sizes, int n_in,
                              void* d_out, int out_size, void* d_ws, size_t ws_size,
                              hipStream_t stream) {
  (void)in_sizes; (void)n_in; (void)out_size;
  const float* queries = (const float*)d_in[0];
  const float* keys    = (const float*)d_in[1];
  const float* values  = (const float*)d_in[2];
  const int*   mask    = (const int*)d_in[3];
  const float* Wq      = (const float*)d_in[4];
  const float* Wk      = (const float*)d_in[5];
  const float* Wv      = (const float*)d_in[6];
  const float* Wo      = (const float*)d_in[7];
  const float* bo      = (const float*)d_in[8];

  const size_t NEED = (size_t)76 * 1024 * 1024;
  if (ws_size < NEED) return;

  char* ws = (char*)d_ws;
  short* wqb  = (short*)(ws + (24u << 20)); // weights, stride 2 MiB
  short* wob  = (short*)(ws + (30u << 20));
  unsigned long long* mbits = (unsigned long long*)(ws + (32u << 20)); // 1 MiB
  short* Qp   = (short*)(ws + (40u << 20));
  short* Kp   = (short*)(ws + (48u << 20));
  short* VTp  = (short*)(ws + (56u << 20));
  short* ao   = (short*)(ws + (64u << 20));

  const int NW = EMBED * EMBED;

  CvtArgs ca;
  ca.src[0] = Wq; ca.dst[0] = wqb;                         ca.n[0] = NW;
  ca.src[1] = Wk; ca.dst[1] = (short*)(ws + (26u << 20));  ca.n[1] = NW;
  ca.src[2] = Wv; ca.dst[2] = (short*)(ws + (28u << 20));  ca.n[2] = NW;
  ca.src[3] = Wo; ca.dst[3] = wob;                         ca.n[3] = NW;
  cvt_bf16<<<dim3(512, 4), 256, 0, stream>>>(ca);

  maskpack<<<dim3(32768), 256, 0, stream>>>(mask, mbits);

  gemm_qkv<<<dim3(768), 256, 0, stream>>>(queries, keys, values, wqb, Qp, Kp, VTp);

  attn256<<<dim3(512), 256, 0, stream>>>(Qp, Kp, VTp, mbits, ao);

  gemm_out<<<dim3(512), 256, 0, stream>>>(ao, wob, (float*)d_out, bo);
}